// Round 3
// baseline (241.151 us; speedup 1.0000x reference)
//
#include <hip/hip_runtime.h>
#include <cstdint>
#include <cstddef>

#define N_COLS 4096
#define TPB 256
#define NCOPY 8
#define HSTR 12              // 8 copies + 4 pad words; 48B stride keeps b128 16B-aligned
#define NHWORDS (256 * HSTR) // 3072 words = 12 KB
#define CAP 1024

// --- kernel 1: boost factors, double-precision exp rounded to fp32 ---
__global__ void boost_kernel(const float* __restrict__ dc,
                             const int* __restrict__ kp,
                             float* __restrict__ bf) {
    int i = blockIdx.x * blockDim.x + threadIdx.x;
    if (i < N_COLS) {
        float td = (float)kp[0] / (float)N_COLS;   // float32(k)/float32(n), like ref
        float arg = td - dc[i];                    // fp32 subtract, like ref
        bf[i] = (float)exp((double)arg);           // ~correctly-rounded fp32 exp
    }
}

__device__ __forceinline__ uint32_t orderable(float f) {
    uint32_t u = __float_as_uint(f);
    return (u & 0x80000000u) ? ~u : (u | 0x80000000u);  // float order == uint order
}

// one block per row; 16 boosted bit patterns per thread held in registers
__global__ __launch_bounds__(TPB) void kwinner_kernel(
    const float* __restrict__ x, const float* __restrict__ bf,
    const int* __restrict__ kp, float* __restrict__ out)
{
    __shared__ uint32_t s_hist[NHWORDS];   // bin-major: [bin*HSTR + copy]
    __shared__ uint32_t s_cnt[256];
    __shared__ uint32_t s_cand[CAP];
    __shared__ uint32_t s_m, s_m2, s_sel;

    const int tid  = threadIdx.x;
    const int lane = tid & 63;
    const uint32_t copy = (uint32_t)(lane & (NCOPY - 1));
    const size_t row = blockIdx.x;
    const float4* xr = (const float4*)(x + row * (size_t)N_COLS);
    const float4* br = (const float4*)bf;
    float4* orow = (float4*)(out + row * (size_t)N_COLS);

    uint32_t u[16];
    #pragma unroll
    for (int j = 0; j < 4; ++j) {
        float4 v = xr[tid + j * TPB];
        float4 b = br[tid + j * TPB];
        u[j * 4 + 0] = orderable(v.x * b.x);
        u[j * 4 + 1] = orderable(v.y * b.y);
        u[j * 4 + 2] = orderable(v.z * b.z);
        u[j * 4 + 3] = orderable(v.w * b.w);
    }

    // init: clear histogram (vectorized) + counters
    {
        uint4* h4 = (uint4*)s_hist;
        uint4 z; z.x = z.y = z.z = z.w = 0u;
        #pragma unroll
        for (int j = 0; j < 3; ++j) h4[tid + j * TPB] = z;   // 768 uint4 total
    }
    if (tid == 0) { s_m = 0; s_m2 = 0; }
    __syncthreads();

    // wave-aggregated scatter of `val` where pred, positions from *counter
    auto wave_scatter = [&](uint32_t val, bool pred, uint32_t* buf,
                            uint32_t* counter, uint32_t cap) {
        unsigned long long msk = __ballot(pred);
        if (msk) {                                 // wave-uniform branch
            int leader = __builtin_ctzll(msk);
            uint32_t base = 0;
            if (lane == leader) base = atomicAdd(counter, (uint32_t)__popcll(msk));
            base = (uint32_t)__shfl((int)base, leader, 64);
            if (pred) {
                uint32_t off = __builtin_amdgcn_mbcnt_hi(
                    (uint32_t)(msk >> 32),
                    __builtin_amdgcn_mbcnt_lo((uint32_t)msk, 0));
                uint32_t p = base + off;
                if (p < cap) buf[p] = val;
            }
        }
    };

    // T0 = orderable(1.10f): boosted < 1.10 can never reach rank 409 of 4096
    // for this data (m ~= 556 +- 22); exactness guarded by count check + fallback.
    const uint32_t T0 = 0xBF8CCCCDu;
    #pragma unroll
    for (int e = 0; e < 16; ++e)
        wave_scatter(u[e], u[e] >= T0, s_cand, &s_m, CAP);
    __syncthreads();

    const uint32_t k = (uint32_t)kp[0];
    const uint32_t m = s_m;
    uint32_t rem = k;
    uint32_t prefix = 0;
    uint32_t thr;

    // sum the NCOPY copies of bin `tid`, zero them, publish to s_cnt
    auto reduce_bins = [&]() {
        uint4 a  = *(const uint4*)&s_hist[tid * HSTR];
        uint4 b2 = *(const uint4*)&s_hist[tid * HSTR + 4];
        uint4 z; z.x = z.y = z.z = z.w = 0u;
        *(uint4*)&s_hist[tid * HSTR]     = z;
        *(uint4*)&s_hist[tid * HSTR + 4] = z;
        s_cnt[tid] = a.x + a.y + a.z + a.w + b2.x + b2.y + b2.z + b2.w;
    };

    // replicated per-wave suffix-scan of s_cnt; picks digit, updates rem
    auto scan_digit = [&](uint32_t& remr) -> uint32_t {
        uint4 v = ((const uint4*)s_cnt)[lane];
        uint32_t s3 = v.w, s2 = v.z + s3, s1 = v.y + s2, s0 = v.x + s1;
        uint32_t T = s0;
        #pragma unroll
        for (int off = 1; off < 64; off <<= 1) {
            uint32_t t = (uint32_t)__shfl_down((int)T, off, 64);
            if (lane + off < 64) T += t;
        }
        uint32_t Tex = T - s0;   // sum over lanes > lane
        uint32_t S0 = Tex + s0, S1 = Tex + s1, S2 = Tex + s2, S3 = Tex + s3;
        int b = -1; uint32_t sn = 0;
        if (S3 >= remr)      { b = 3; sn = S3 - v.w; }
        else if (S2 >= remr) { b = 2; sn = S2 - v.z; }
        else if (S1 >= remr) { b = 1; sn = S1 - v.y; }
        else if (S0 >= remr) { b = 0; sn = S0 - v.x; }
        uint32_t packed = (b >= 0)
            ? (((uint32_t)(4 * lane + b + 1) << 16) | sn)   // sn < 65536
            : 0u;
        #pragma unroll
        for (int off = 1; off < 64; off <<= 1) {
            uint32_t o = (uint32_t)__shfl_xor((int)packed, off, 64);
            packed = packed > o ? packed : o;
        }
        remr -= (packed & 0xFFFFu);
        return (packed >> 16) - 1u;
    };

    if (m >= k && m <= CAP) {
        // candidates into regs (<=4 per thread)
        uint32_t cv[4]; bool cp[4];
        #pragma unroll
        for (int j = 0; j < 4; ++j) {
            uint32_t idx = (uint32_t)tid + j * TPB;
            cp[j] = idx < m;
            cv[j] = cp[j] ? s_cand[idx] : 0u;
        }
        // pass A: bits[31:24] over candidates
        #pragma unroll
        for (int j = 0; j < 4; ++j)
            if (cp[j]) atomicAdd(&s_hist[((cv[j] >> 24) & 255u) * HSTR + copy], 1u);
        __syncthreads();
        reduce_bins();
        __syncthreads();
        prefix = scan_digit(rem) << 24;

        // pass B: bits[23:16] among candidates matching byte 1
        #pragma unroll
        for (int j = 0; j < 4; ++j)
            if (cp[j] && ((cv[j] ^ prefix) & 0xFF000000u) == 0u)
                atomicAdd(&s_hist[((cv[j] >> 16) & 255u) * HSTR + copy], 1u);
        __syncthreads();
        reduce_bins();
        __syncthreads();
        prefix |= scan_digit(rem) << 16;

        // compact candidates matching the 16-bit prefix into s_hist area (free now)
        uint32_t* s_cand2 = s_hist;
        #pragma unroll
        for (int j = 0; j < 4; ++j)
            wave_scatter(cv[j],
                         cp[j] && ((cv[j] ^ prefix) & 0xFFFF0000u) == 0u,
                         s_cand2, &s_m2, (uint32_t)NHWORDS);
        __syncthreads();
        const uint32_t m2 = s_m2;   // <= m <= CAP, fits

        if (tid < 64) {   // wave 0: exact bitwise descent over low 16 bits
            uint32_t cv2[16];
            #pragma unroll
            for (int r = 0; r < 16; ++r) {
                uint32_t idx = (uint32_t)(r * 64) + lane;
                cv2[r] = (idx < m2) ? s_cand2[idx] : ~prefix;  // inval never matches
            }
            uint32_t cur = 0;
            #pragma unroll
            for (int bpos = 15; bpos >= 0; --bpos) {
                uint32_t t  = prefix | cur | (1u << bpos);
                uint32_t mk = ~((1u << bpos) - 1u);
                uint32_t c = 0;
                #pragma unroll
                for (int r = 0; r < 16; ++r)
                    if ((uint32_t)(r * 64) < m2)   // wave-uniform skip
                        c += (uint32_t)__popcll(__ballot(((cv2[r] ^ t) & mk) == 0u));
                if (c >= rem) cur |= (1u << bpos);
                else          rem -= c;
            }
            if (tid == 0) s_sel = prefix | cur;
        }
        __syncthreads();
        thr = s_sel;
    } else {
        // adversarial-data fallback: exact 4-pass radix over all elements
        const uint32_t pmasks[4] = {0u, 0xFF000000u, 0xFFFF0000u, 0xFFFFFF00u};
        rem = k; prefix = 0;
        #pragma unroll 1
        for (int pass = 0; pass < 4; ++pass) {
            const int shift = 24 - pass * 8;
            const uint32_t pm = pmasks[pass];
            #pragma unroll
            for (int e = 0; e < 16; ++e)
                if (((u[e] ^ prefix) & pm) == 0u)
                    atomicAdd(&s_hist[((u[e] >> shift) & 255u) * HSTR + copy], 1u);
            __syncthreads();
            reduce_bins();
            __syncthreads();
            prefix |= scan_digit(rem) << shift;
        }
        thr = prefix;
    }

    // epilogue: reload x (L2/L3-hot), apply exact mask
    #pragma unroll
    for (int j = 0; j < 4; ++j) {
        float4 v = xr[tid + j * TPB];
        float4 o;
        o.x = (u[j * 4 + 0] >= thr) ? v.x : 0.0f;
        o.y = (u[j * 4 + 1] >= thr) ? v.y : 0.0f;
        o.z = (u[j * 4 + 2] >= thr) ? v.z : 0.0f;
        o.w = (u[j * 4 + 3] >= thr) ? v.w : 0.0f;
        orow[tid + j * TPB] = o;
    }
}

extern "C" void kernel_launch(void* const* d_in, const int* in_sizes, int n_in,
                              void* d_out, int out_size, void* d_ws, size_t ws_size,
                              hipStream_t stream) {
    const float* x  = (const float*)d_in[0];
    const float* dc = (const float*)d_in[1];
    const int*   kp = (const int*)d_in[2];
    float* out = (float*)d_out;
    float* bf  = (float*)d_ws;                 // 4096 floats of scratch

    const int n    = in_sizes[1];              // 4096
    const int rows = in_sizes[0] / n;          // 8192

    boost_kernel<<<(n + TPB - 1) / TPB, TPB, 0, stream>>>(dc, kp, bf);
    kwinner_kernel<<<rows, TPB, 0, stream>>>(x, bf, kp, out);
}

// Round 4
// 230.622 us; speedup vs baseline: 1.0457x; 1.0457x over previous
//
#include <hip/hip_runtime.h>
#include <cstdint>
#include <cstddef>

#define N_COLS 4096
#define TPB 256
#define NCOPY 8
#define HSTR 12              // 8 copies + 4 pad words (48 B stride, 16B-aligned)
#define NHWORDS (256 * HSTR) // 3072 words = 12 KB
#define SURV_CAP 64

// --- kernel 1: boost factors, double-precision exp rounded to fp32 ---
__global__ void boost_kernel(const float* __restrict__ dc,
                             const int* __restrict__ kp,
                             float* __restrict__ bf) {
    int i = blockIdx.x * blockDim.x + threadIdx.x;
    if (i < N_COLS) {
        float td = (float)kp[0] / (float)N_COLS;   // float32(k)/float32(n), like ref
        float arg = td - dc[i];                    // fp32 subtract, like ref
        bf[i] = (float)exp((double)arg);           // ~correctly-rounded fp32 exp
    }
}

__device__ __forceinline__ uint32_t orderable(uint32_t u) {
    return (u & 0x80000000u) ? ~u : (u | 0x80000000u);  // float order == uint order
}

// one block per row; 16 boosted values per thread in registers
__global__ __launch_bounds__(TPB) void kwinner_kernel(
    const float* __restrict__ x, const float* __restrict__ bf,
    const int* __restrict__ kp, float* __restrict__ out)
{
    __shared__ uint32_t s_hist[NHWORDS];   // bin-major: [bin*HSTR + copy]
    __shared__ uint32_t s_cnt[256];        // fallback only
    __shared__ uint32_t s_cand[SURV_CAP];
    __shared__ uint32_t s_m2;

    const int tid  = threadIdx.x;
    const int lane = tid & 63;
    const uint32_t copy = (uint32_t)(tid & (NCOPY - 1));
    const size_t row = blockIdx.x;
    const float4* xr = (const float4*)(x + row * (size_t)N_COLS);
    const float4* br = (const float4*)bf;
    float4* orow = (float4*)(out + row * (size_t)N_COLS);

    float4 xv[4];
    float xb[16];
    #pragma unroll
    for (int j = 0; j < 4; ++j) {
        float4 v = xr[tid + j * TPB];
        float4 b = br[tid + j * TPB];
        xv[j] = v;
        xb[j * 4 + 0] = v.x * b.x;
        xb[j * 4 + 1] = v.y * b.y;
        xb[j * 4 + 2] = v.z * b.z;
        xb[j * 4 + 3] = v.w * b.w;
    }

    // clear histogram (vectorized) + survivor counter
    {
        uint4* h4 = (uint4*)s_hist;
        uint4 z; z.x = z.y = z.z = z.w = 0u;
        #pragma unroll
        for (int j = 0; j < 3; ++j) h4[tid + j * TPB] = z;
    }
    if (tid == 0) s_m2 = 0;
    __syncthreads();

    // single histogram pass over candidates >= T0 with the composite digit
    // d = min((bits>>16) - 0x3F80, 255): monotone for all floats >= 1.0.
    const float T0f = 1.10f;   // performance heuristic only; exactness guarded below
    #pragma unroll
    for (int e = 0; e < 16; ++e) {
        if (xb[e] >= T0f) {
            uint32_t d = (__float_as_uint(xb[e]) >> 16) - 0x3F80u;
            d = d > 255u ? 255u : d;
            atomicAdd(&s_hist[d * HSTR + copy], 1u);
        }
    }
    __syncthreads();

    const uint32_t k = (uint32_t)kp[0];
    uint32_t rem = k;

    // fused copy-reduce + suffix-scan + digit pick, replicated on every wave
    uint32_t dsel;
    uint32_t packed;
    {
        uint32_t vv[4];
        const uint32_t b0 = (uint32_t)lane * 4u;
        #pragma unroll
        for (int i = 0; i < 4; ++i) {
            uint4 a  = *(const uint4*)&s_hist[(b0 + i) * HSTR];
            uint4 b2 = *(const uint4*)&s_hist[(b0 + i) * HSTR + 4];
            vv[i] = a.x + a.y + a.z + a.w + b2.x + b2.y + b2.z + b2.w;
        }
        uint32_t s3 = vv[3], s2 = vv[2] + s3, s1 = vv[1] + s2, s0 = vv[0] + s1;
        uint32_t T = s0;
        #pragma unroll
        for (int off = 1; off < 64; off <<= 1) {
            uint32_t t = (uint32_t)__shfl_down((int)T, off, 64);
            if (lane + off < 64) T += t;
        }
        uint32_t Tex = T - s0;   // sum over lanes > lane
        uint32_t S0 = Tex + s0, S1 = Tex + s1, S2 = Tex + s2, S3 = Tex + s3;
        int b = -1; uint32_t sn = 0;
        if (S3 >= rem)      { b = 3; sn = S3 - vv[3]; }
        else if (S2 >= rem) { b = 2; sn = S2 - vv[2]; }
        else if (S1 >= rem) { b = 1; sn = S1 - vv[1]; }
        else if (S0 >= rem) { b = 0; sn = S0 - vv[0]; }
        packed = (b >= 0) ? ((((uint32_t)(4 * lane + b + 1)) << 16) | sn) : 0u;
        #pragma unroll
        for (int off = 1; off < 64; off <<= 1) {
            uint32_t o = (uint32_t)__shfl_xor((int)packed, off, 64);
            packed = packed > o ? packed : o;
        }
        dsel = (packed >> 16) - 1u;      // selected digit (if packed != 0)
        rem -= (packed & 0xFFFFu);       // rank within selected bin
    }

    float thr = 0.0f;
    bool need_fallback = (packed == 0u) || (dsel == 255u);

    if (!need_fallback) {
        const uint32_t hi16 = 0x3F80u + dsel;
        // scatter survivors (order irrelevant); may include a few elements in
        // [1.09375, T0) when dsel==0x0C — all strictly below every histogrammed
        // member, and rem <= member count, so the rem-th largest is unaffected.
        #pragma unroll
        for (int e = 0; e < 16; ++e) {
            uint32_t ub = __float_as_uint(xb[e]);
            if ((ub >> 16) == hi16) {
                uint32_t pos = atomicAdd(&s_m2, 1u);
                if (pos < SURV_CAP) s_cand[pos] = ub;
            }
        }
        __syncthreads();
        const uint32_t m2 = s_m2;        // block-uniform broadcast read
        if (m2 <= SURV_CAP) {
            // replicated 16-bit ballot descent: every wave loads the same
            // survivors, so every wave's ballot counts are the global counts.
            uint32_t cv = ((uint32_t)lane < m2) ? s_cand[lane] : ((~hi16) << 16);
            uint32_t cur = 0;
            #pragma unroll
            for (int bpos = 15; bpos >= 0; --bpos) {
                uint32_t t  = (hi16 << 16) | cur | (1u << bpos);
                uint32_t mk = ~((1u << bpos) - 1u);
                uint32_t c  = (uint32_t)__popcll(__ballot(((cv ^ t) & mk) == 0u));
                if (c >= rem) cur |= (1u << bpos);
                else          rem -= c;
            }
            thr = __uint_as_float((hi16 << 16) | cur);
        } else {
            need_fallback = true;
        }
    }

    if (need_fallback) {
        // exact 4-pass orderable radix over all 4096 elements (any input)
        __syncthreads();
        {
            uint4* h4 = (uint4*)s_hist;
            uint4 z; z.x = z.y = z.z = z.w = 0u;
            #pragma unroll
            for (int j = 0; j < 3; ++j) h4[tid + j * TPB] = z;
        }
        __syncthreads();
        uint32_t prefix = 0;
        rem = k;
        const uint32_t pmasks[4] = {0u, 0xFF000000u, 0xFFFF0000u, 0xFFFFFF00u};
        #pragma unroll 1
        for (int pass = 0; pass < 4; ++pass) {
            const int shift = 24 - pass * 8;
            const uint32_t pm = pmasks[pass];
            #pragma unroll
            for (int e = 0; e < 16; ++e) {
                uint32_t ou = orderable(__float_as_uint(xb[e]));
                if (((ou ^ prefix) & pm) == 0u)
                    atomicAdd(&s_hist[((ou >> shift) & 255u) * HSTR + copy], 1u);
            }
            __syncthreads();
            // reduce copies of bin `tid`, zero them for the next pass
            {
                uint4 a  = *(const uint4*)&s_hist[tid * HSTR];
                uint4 b2 = *(const uint4*)&s_hist[tid * HSTR + 4];
                uint4 z; z.x = z.y = z.z = z.w = 0u;
                *(uint4*)&s_hist[tid * HSTR]     = z;
                *(uint4*)&s_hist[tid * HSTR + 4] = z;
                s_cnt[tid] = a.x + a.y + a.z + a.w + b2.x + b2.y + b2.z + b2.w;
            }
            __syncthreads();
            // replicated suffix-scan digit pick over s_cnt
            uint4 v = ((const uint4*)s_cnt)[lane];
            uint32_t s3 = v.w, s2 = v.z + s3, s1 = v.y + s2, s0 = v.x + s1;
            uint32_t T = s0;
            #pragma unroll
            for (int off = 1; off < 64; off <<= 1) {
                uint32_t t = (uint32_t)__shfl_down((int)T, off, 64);
                if (lane + off < 64) T += t;
            }
            uint32_t Tex = T - s0;
            uint32_t S0 = Tex + s0, S1 = Tex + s1, S2 = Tex + s2, S3 = Tex + s3;
            int b = -1; uint32_t sn = 0;
            if (S3 >= rem)      { b = 3; sn = S3 - v.w; }
            else if (S2 >= rem) { b = 2; sn = S2 - v.z; }
            else if (S1 >= rem) { b = 1; sn = S1 - v.y; }
            else if (S0 >= rem) { b = 0; sn = S0 - v.x; }
            uint32_t pk = (b >= 0) ? ((((uint32_t)(4 * lane + b + 1)) << 16) | sn) : 0u;
            #pragma unroll
            for (int off = 1; off < 64; off <<= 1) {
                uint32_t o = (uint32_t)__shfl_xor((int)pk, off, 64);
                pk = pk > o ? pk : o;
            }
            prefix |= ((pk >> 16) - 1u) << shift;
            rem -= (pk & 0xFFFFu);
        }
        // orderable-space -> float bits
        uint32_t tu = (prefix & 0x80000000u) ? (prefix & 0x7FFFFFFFu) : ~prefix;
        thr = __uint_as_float(tu);
    }

    // epilogue: mask from boosted (regs) vs thr, values from x (regs)
    #pragma unroll
    for (int j = 0; j < 4; ++j) {
        float4 o;
        o.x = (xb[j * 4 + 0] >= thr) ? xv[j].x : 0.0f;
        o.y = (xb[j * 4 + 1] >= thr) ? xv[j].y : 0.0f;
        o.z = (xb[j * 4 + 2] >= thr) ? xv[j].z : 0.0f;
        o.w = (xb[j * 4 + 3] >= thr) ? xv[j].w : 0.0f;
        orow[tid + j * TPB] = o;
    }
}

extern "C" void kernel_launch(void* const* d_in, const int* in_sizes, int n_in,
                              void* d_out, int out_size, void* d_ws, size_t ws_size,
                              hipStream_t stream) {
    const float* x  = (const float*)d_in[0];
    const float* dc = (const float*)d_in[1];
    const int*   kp = (const int*)d_in[2];
    float* out = (float*)d_out;
    float* bf  = (float*)d_ws;                 // 4096 floats of scratch

    const int n    = in_sizes[1];              // 4096
    const int rows = in_sizes[0] / n;          // 8192

    boost_kernel<<<(n + TPB - 1) / TPB, TPB, 0, stream>>>(dc, kp, bf);
    kwinner_kernel<<<rows, TPB, 0, stream>>>(x, bf, kp, out);
}